// Round 5
// baseline (220.586 us; speedup 1.0000x reference)
//
#include <hip/hip_runtime.h>

// Cosine-similarity attention context:
//   cos[s] = (keys[s,:].q) / (||q|| ||keys[s,:]||);  ctx = sum_s cos[s]*keys[s,:]
// keys = 32768 x 1024 f32 (128 MiB).
//
// R4 -> R5: fused single-pass kernel is ~3x over the streaming floor; theory:
// per-row serial chain (load -> 12 ds_bpermute hops -> score -> consume same
// registers) limits it, and occupancy didn't help (R4 regressed). Orthogonal
// structure: TWO PASSES.
//  pass1: wave-per-row shuffle reduce -> cos[s] only (128 KiB). Chains retire
//         independently; no downstream register reuse.
//  pass2: column-parallel: thread owns 4 cols, iterates rows,
//         acc += cos[s]*keys[s][cols]. cos[s] is wave-uniform (scalar bcast),
//         fully coalesced, ZERO cross-lane ops/barriers. keys are L3-resident
//         from pass1 (128 MiB < 256 MiB L3) -> ~L3 BW, ~zero extra HBM fetch.
//  pass3: sum 256 block-partials (1 MiB, L2-hot) -> out. No atomics anywhere.

constexpr int H   = 1024;
constexpr int TPB = 256;
constexpr int WPB = TPB / 64;
constexpr int P1_BLOCKS = 512;    // 2048 waves, 16 rows/wave
constexpr int P2_BLOCKS = 256;    // 128 rows/block, full column coverage/block

// ---------------- pass 1: cos scores ----------------
__global__ __launch_bounds__(TPB, 2)
void p1_scores(const float* __restrict__ q,
               const float* __restrict__ keys,
               int S,
               float* __restrict__ cosv)
{
    const int lane  = threadIdx.x & 63;
    const int wave  = threadIdx.x >> 6;
    const int gwave = blockIdx.x * WPB + wave;
    const int nwaves = gridDim.x * WPB;

    const float4* q4 = reinterpret_cast<const float4*>(q);
    const float4* k4 = reinterpret_cast<const float4*>(keys);

    float4 qv[4];
#pragma unroll
    for (int j = 0; j < 4; ++j) qv[j] = q4[j * 64 + lane];

    float qsq = 0.f;
#pragma unroll
    for (int j = 0; j < 4; ++j)
        qsq += qv[j].x * qv[j].x + qv[j].y * qv[j].y +
               qv[j].z * qv[j].z + qv[j].w * qv[j].w;
#pragma unroll
    for (int off = 32; off > 0; off >>= 1) qsq += __shfl_down(qsq, off, 64);
    const float inv_qn = rsqrtf(__shfl(qsq, 0, 64));

    // prefetched row loop; nothing consumes kv after the reduce -> chains
    // from successive rows overlap freely.
    int row = gwave;
    float4 kv[4];
    if (row < S) {
        const float4* kr = k4 + (size_t)row * (H / 4);
#pragma unroll
        for (int j = 0; j < 4; ++j) kv[j] = kr[j * 64 + lane];
    }
    while (row < S) {
        const int nrow = row + nwaves;
        float4 kn[4];
        if (nrow < S) {
            const float4* kr = k4 + (size_t)nrow * (H / 4);
#pragma unroll
            for (int j = 0; j < 4; ++j) kn[j] = kr[j * 64 + lane];
        }

        float dot = 0.f, ksq = 0.f;
#pragma unroll
        for (int j = 0; j < 4; ++j) {
            dot += kv[j].x * qv[j].x + kv[j].y * qv[j].y +
                   kv[j].z * qv[j].z + kv[j].w * qv[j].w;
            ksq += kv[j].x * kv[j].x + kv[j].y * kv[j].y +
                   kv[j].z * kv[j].z + kv[j].w * kv[j].w;
        }
#pragma unroll
        for (int off = 32; off > 0; off >>= 1) {
            dot += __shfl_down(dot, off, 64);
            ksq += __shfl_down(ksq, off, 64);
        }
        if (lane == 0)
            cosv[row] = dot * inv_qn * rsqrtf(ksq);

#pragma unroll
        for (int j = 0; j < 4; ++j) kv[j] = kn[j];
        row = nrow;
    }
}

// ---------------- pass 2: column-parallel weighted sum ----------------
__global__ __launch_bounds__(TPB)
void p2_ctx(const float* __restrict__ keys,
            const float* __restrict__ cosv,
            int S,
            float* __restrict__ partials)
{
    const float4* k4 = reinterpret_cast<const float4*>(keys);
    const int t   = threadIdx.x;             // float4 column index 0..255
    const int rpb = S / P2_BLOCKS;           // 128 rows per block
    const int r0  = blockIdx.x * rpb;

    float4 acc = make_float4(0.f, 0.f, 0.f, 0.f);
    // unroll 4: 4 independent row loads in flight; cos[] is wave-uniform
#pragma unroll 1
    for (int r = r0; r < r0 + rpb; r += 4) {
        float4 k0 = k4[(size_t)(r + 0) * (H / 4) + t];
        float4 k1 = k4[(size_t)(r + 1) * (H / 4) + t];
        float4 k2 = k4[(size_t)(r + 2) * (H / 4) + t];
        float4 k3 = k4[(size_t)(r + 3) * (H / 4) + t];
        float c0 = cosv[r + 0], c1 = cosv[r + 1];
        float c2 = cosv[r + 2], c3 = cosv[r + 3];
        acc.x += c0 * k0.x; acc.y += c0 * k0.y; acc.z += c0 * k0.z; acc.w += c0 * k0.w;
        acc.x += c1 * k1.x; acc.y += c1 * k1.y; acc.z += c1 * k1.z; acc.w += c1 * k1.w;
        acc.x += c2 * k2.x; acc.y += c2 * k2.y; acc.z += c2 * k2.z; acc.w += c2 * k2.w;
        acc.x += c3 * k3.x; acc.y += c3 * k3.y; acc.z += c3 * k3.z; acc.w += c3 * k3.w;
    }
    reinterpret_cast<float4*>(partials)[(size_t)blockIdx.x * (H / 4) + t] = acc;
}

// ---------------- pass 3: reduce 256 partials -> out ----------------
__global__ __launch_bounds__(TPB)
void p3_reduce(const float* __restrict__ partials, float* __restrict__ out)
{
    const int col = blockIdx.x * TPB + threadIdx.x;   // 0..1023
    float s = 0.f;
#pragma unroll 8
    for (int r = 0; r < P2_BLOCKS; ++r)
        s += partials[(size_t)r * H + col];
    out[col] = s;
}

extern "C" void kernel_launch(void* const* d_in, const int* in_sizes, int n_in,
                              void* d_out, int out_size, void* d_ws, size_t ws_size,
                              hipStream_t stream)
{
    const float* q    = (const float*)d_in[0];
    const float* keys = (const float*)d_in[1];
    float* out        = (float*)d_out;
    const int S = in_sizes[1] / H;

    float* cosv     = (float*)d_ws;                    // S floats (128 KiB)
    float* partials = (float*)d_ws + S;                // P2_BLOCKS*H (1 MiB)

    p1_scores<<<P1_BLOCKS, TPB, 0, stream>>>(q, keys, S, cosv);
    p2_ctx   <<<P2_BLOCKS, TPB, 0, stream>>>(keys, cosv, S, partials);
    p3_reduce<<<H / TPB,   TPB, 0, stream>>>(partials, out);
}

// Round 6
// 201.004 us; speedup vs baseline: 1.0974x; 1.0974x over previous
//
#include <hip/hip_runtime.h>

// Cosine-similarity attention context:
//   cos[s] = (keys[s,:].q) / (||q|| ||keys[s,:]||);  ctx = sum_s cos[s]*keys[s,:]
// keys = 32768 x 1024 f32 (128 MiB), single streaming pass.
//
// R5 post-mortem: second keys pass is NOT L3-served (harness streams 768 MB of
// poison/restore through caches every iteration) -> back to fused single pass.
// R6 theory: R1/R3 main had VGPR=44 -> compiler dropped the prefetch (can't
// hold qv+kv+kn+acc in 44 regs), serializing load->12-hop shuffle->FMA per row.
// Fix: 4 rows/iteration, explicit 4-row double buffer (16 float4 loads in
// flight/wave), merged 8-chain shfl_xor butterfly (6 dep levels for all 8
// partials, every lane gets the sum -> no broadcast shuffles).

constexpr int H    = 1024;
constexpr int TPB  = 256;
constexpr int WPB  = TPB / 64;
constexpr int ROWS = 4;            // rows per iteration per wave
constexpr int NBLOCKS = 512;       // 2048 waves; stride = 8192 rows; 4 iters

__global__ __launch_bounds__(TPB, 2)
void cosctx_main(const float* __restrict__ q,
                 const float* __restrict__ keys,
                 int S,
                 float* __restrict__ ws)
{
    const int lane  = threadIdx.x & 63;
    const int wave  = threadIdx.x >> 6;
    const int gwave = blockIdx.x * WPB + wave;
    const int nwaves = gridDim.x * WPB;
    const int stride = nwaves * ROWS;

    const float4* q4 = reinterpret_cast<const float4*>(q);
    const float4* k4 = reinterpret_cast<const float4*>(keys);

    // --- query fragment + 1/||q|| (butterfly: every lane gets the sum) ---
    float4 qv[4];
#pragma unroll
    for (int j = 0; j < 4; ++j) qv[j] = q4[j * 64 + lane];

    float qsq = 0.f;
#pragma unroll
    for (int j = 0; j < 4; ++j)
        qsq += qv[j].x * qv[j].x + qv[j].y * qv[j].y +
               qv[j].z * qv[j].z + qv[j].w * qv[j].w;
#pragma unroll
    for (int off = 32; off > 0; off >>= 1) qsq += __shfl_xor(qsq, off, 64);
    const float inv_qn = rsqrtf(qsq);

    float4 acc[4];
#pragma unroll
    for (int j = 0; j < 4; ++j) acc[j] = make_float4(0.f, 0.f, 0.f, 0.f);

    // --- 4-row batches, explicit double buffer ---
    float4 kv[ROWS][4], kn[ROWS][4];
    int base = gwave * ROWS;

#pragma unroll
    for (int r = 0; r < ROWS; ++r) {
        if (base + r < S) {
            const float4* kr = k4 + (size_t)(base + r) * (H / 4);
#pragma unroll
            for (int j = 0; j < 4; ++j) kv[r][j] = kr[j * 64 + lane];
        }
    }

    while (base < S) {
        const int nbase = base + stride;
        if (nbase < S) {
#pragma unroll
            for (int r = 0; r < ROWS; ++r) {
                if (nbase + r < S) {
                    const float4* kr = k4 + (size_t)(nbase + r) * (H / 4);
#pragma unroll
                    for (int j = 0; j < 4; ++j) kn[r][j] = kr[j * 64 + lane];
                }
            }
        }

        // in-lane partials for 4 rows (8 independent reduction chains)
        float d[ROWS], k2[ROWS];
#pragma unroll
        for (int r = 0; r < ROWS; ++r) {
            float dot = 0.f, ksq = 0.f;
#pragma unroll
            for (int j = 0; j < 4; ++j) {
                dot += kv[r][j].x * qv[j].x + kv[r][j].y * qv[j].y +
                       kv[r][j].z * qv[j].z + kv[r][j].w * qv[j].w;
                ksq += kv[r][j].x * kv[r][j].x + kv[r][j].y * kv[r][j].y +
                       kv[r][j].z * kv[r][j].z + kv[r][j].w * kv[r][j].w;
            }
            d[r] = dot; k2[r] = ksq;
        }

        // merged butterfly: 6 levels x 8 parallel chains; all lanes get sums
#pragma unroll
        for (int off = 32; off > 0; off >>= 1) {
#pragma unroll
            for (int r = 0; r < ROWS; ++r) {
                d[r]  += __shfl_xor(d[r],  off, 64);
                k2[r] += __shfl_xor(k2[r], off, 64);
            }
        }

#pragma unroll
        for (int r = 0; r < ROWS; ++r) {
            const float score = (base + r < S)
                ? d[r] * inv_qn * rsqrtf(k2[r]) : 0.f;
#pragma unroll
            for (int j = 0; j < 4; ++j) {
                acc[j].x += score * kv[r][j].x;
                acc[j].y += score * kv[r][j].y;
                acc[j].z += score * kv[r][j].z;
                acc[j].w += score * kv[r][j].w;
            }
        }

#pragma unroll
        for (int r = 0; r < ROWS; ++r)
#pragma unroll
            for (int j = 0; j < 4; ++j) kv[r][j] = kn[r][j];
        base = nbase;
    }

    // --- block reduce: 4 wave-partials -> 1 block-partial [H] ---
    __shared__ float sacc[WPB][H];   // 16 KiB
    float4* sa4 = reinterpret_cast<float4*>(sacc[wave]);
#pragma unroll
    for (int j = 0; j < 4; ++j) sa4[j * 64 + lane] = acc[j];
    __syncthreads();

    float4 v = make_float4(0.f, 0.f, 0.f, 0.f);
#pragma unroll
    for (int w = 0; w < WPB; ++w) {
        float4 u = reinterpret_cast<const float4*>(sacc[w])[threadIdx.x];
        v.x += u.x; v.y += u.y; v.z += u.z; v.w += u.w;
    }

    reinterpret_cast<float4*>(ws)[(size_t)blockIdx.x * (H / 4) + threadIdx.x] = v;
}

// Sum NBLOCKS x H block-partials (2 MiB) -> out. Atomic-free (R3-proven).
__global__ __launch_bounds__(TPB)
void cosctx_reduce(const float* __restrict__ ws, float* __restrict__ out)
{
    const int col   = blockIdx.x * 64 + (threadIdx.x & 63);
    const int chunk = threadIdx.x >> 6;               // 0..3
    const int r0 = chunk * (NBLOCKS / WPB);           // 128 rows per chunk

    float s = 0.f;
#pragma unroll 8
    for (int r = r0; r < r0 + NBLOCKS / WPB; ++r)
        s += ws[(size_t)r * H + col];

    __shared__ float red[WPB][64];
    red[chunk][threadIdx.x & 63] = s;
    __syncthreads();

    if (threadIdx.x < 64) {
        float t = red[0][threadIdx.x] + red[1][threadIdx.x] +
                  red[2][threadIdx.x] + red[3][threadIdx.x];
        out[blockIdx.x * 64 + threadIdx.x] = t;
    }
}

extern "C" void kernel_launch(void* const* d_in, const int* in_sizes, int n_in,
                              void* d_out, int out_size, void* d_ws, size_t ws_size,
                              hipStream_t stream)
{
    const float* q    = (const float*)d_in[0];
    const float* keys = (const float*)d_in[1];
    float* out        = (float*)d_out;
    const int S = in_sizes[1] / H;

    // 2-node graph, zero atomics, single keys pass.
    cosctx_main<<<NBLOCKS, TPB, 0, stream>>>(q, keys, S, (float*)d_ws);
    cosctx_reduce<<<H / 64, TPB, 0, stream>>>((const float*)d_ws, out);
}